// Round 1
// baseline (1618.954 us; speedup 1.0000x reference)
//
#include <hip/hip_runtime.h>
#include <hip/hip_bf16.h>

// GCN forward: out = sum_{i=0..3} x_i,  x_{i+1} = D^-1/2 (A+I) D^-1/2 (x_i W_i) + b_i
// n = ITEM_NUM+1 = 50001 nodes, D = 128 features, E = 800000 edges, 3 layers.
// All fp32 (reference dtypes). edge_index int32, flat [2,E]: row = [0,E), col = [E,2E).

constexpr int NN = 50001;   // ITEM_NUM + 1
constexpr int D  = 128;

__global__ __launch_bounds__(256)
void k_deg(const int* __restrict__ col, float* __restrict__ deg, int E) {
    int e = blockIdx.x * 256 + threadIdx.x;
    if (e < E) atomicAdd(&deg[col[e]], 1.0f);
}

__global__ __launch_bounds__(256)
void k_dinv(float* deg, int n) {
    int v = blockIdx.x * 256 + threadIdx.x;
    if (v < n) deg[v] = rsqrtf(deg[v] + 1.0f);   // +1 self loop; always > 0
}

__global__ __launch_bounds__(256)
void k_norm(const int* __restrict__ row, const int* __restrict__ col,
            const float* __restrict__ dinv, float* __restrict__ nrm, int E) {
    int e = blockIdx.x * 256 + threadIdx.x;
    if (e < E) nrm[e] = dinv[row[e]] * dinv[col[e]];
}

__global__ __launch_bounds__(256)
void k_copy4(const float* __restrict__ src, float* __restrict__ dst, int n4) {
    int i = blockIdx.x * 256 + threadIdx.x;
    if (i < n4) ((float4*)dst)[i] = ((const float4*)src)[i];
}

// h[n,128] = x[n,128] @ W[128,128]; x tile (64 rows) staged in LDS, W float4-streamed (L2-hot).
__global__ __launch_bounds__(256)
void k_gemm(const float* __restrict__ x, const float* __restrict__ W,
            float* __restrict__ h, int n) {
    __shared__ float xs[64][D];
    int rowBase = blockIdx.x * 64;
    int tid = threadIdx.x;
    for (int i = tid; i < 64 * D / 4; i += 256) {
        int r  = rowBase + (i >> 5);   // (i*4)/128
        int c4 = i & 31;
        float4 v = make_float4(0.f, 0.f, 0.f, 0.f);
        if (r < n) v = ((const float4*)x)[(size_t)r * (D / 4) + c4];
        ((float4*)xs)[i] = v;
    }
    __syncthreads();
    int cg = tid & 31;   // float4 column group (covers 128 cols)
    int rs = tid >> 5;   // row slot 0..7
    for (int rr = rs; rr < 64; rr += 8) {
        int r = rowBase + rr;
        if (r >= n) break;
        float4 acc = make_float4(0.f, 0.f, 0.f, 0.f);
#pragma unroll 4
        for (int k = 0; k < D; k++) {
            float  xv = xs[rr][k];
            float4 w  = ((const float4*)W)[k * (D / 4) + cg];
            acc.x = fmaf(xv, w.x, acc.x);
            acc.y = fmaf(xv, w.y, acc.y);
            acc.z = fmaf(xv, w.z, acc.z);
            acc.w = fmaf(xv, w.w, acc.w);
        }
        ((float4*)h)[(size_t)r * (D / 4) + cg] = acc;
    }
}

// xn[c,:] += nrm[e] * h[r,:] for each edge e=(r,c).  2 edges per 256-block, lane f = feature.
__global__ __launch_bounds__(256)
void k_scatter(const int* __restrict__ row, const int* __restrict__ col,
               const float* __restrict__ nrm, const float* __restrict__ h,
               float* __restrict__ xn, int E) {
    long long idx = (long long)blockIdx.x * 256 + threadIdx.x;
    int e = (int)(idx >> 7);
    int f = (int)(idx & 127);
    if (e < E) {
        int r = row[e], c = col[e];
        float v = h[(size_t)r * D + f] * nrm[e];
        atomicAdd(&xn[(size_t)c * D + f], v);
    }
}

// xn += h*dinv^2 (self loop) + b ; accum += xn
__global__ __launch_bounds__(256)
void k_finish(const float* __restrict__ h, const float* __restrict__ dinv,
              const float* __restrict__ b, float* __restrict__ xn,
              float* __restrict__ accum, int n) {
    int idx = blockIdx.x * 256 + threadIdx.x;
    if (idx < n * D) {
        int v = idx >> 7, f = idx & 127;
        float di  = dinv[v];
        float val = xn[idx] + h[idx] * di * di + b[f];
        xn[idx]    = val;
        accum[idx] += val;
    }
}

extern "C" void kernel_launch(void* const* d_in, const int* in_sizes, int n_in,
                              void* d_out, int out_size, void* d_ws, size_t ws_size,
                              hipStream_t stream) {
    const int*   edge = (const int*)d_in[0];    // [2, E]
    const float* emb  = (const float*)d_in[1];  // [100001, 128]
    const float* W    = (const float*)d_in[2];  // [3, 128, 128]
    const float* b    = (const float*)d_in[3];  // [3, 128]
    float* out = (float*)d_out;                 // [50001, 128]

    const int E = in_sizes[0] / 2;
    const int n = NN;
    const size_t nf = (size_t)n * D;            // 6,400,128 floats
    const int* row = edge;
    const int* col = edge + E;

    // workspace carve-up (all 512B-aligned)
    char* ws = (char*)d_ws;
    float* dinv = (float*)ws;
    size_t off = ((size_t)n * 4 + 511) / 512 * 512;
    float* nrm = (float*)(ws + off); off += (size_t)E * 4;          // 3.2 MB
    float* h   = (float*)(ws + off); off += nf * 4;                 // 25.6 MB
    float* xA  = (float*)(ws + off); off += nf * 4;
    float* xB  = (float*)(ws + off);

    // degree -> dinv -> per-edge norm (once; reused by all 3 layers)
    hipMemsetAsync(dinv, 0, (size_t)n * 4, stream);
    k_deg <<<(E + 255) / 256, 256, 0, stream>>>(col, dinv, E);
    k_dinv<<<(n + 255) / 256, 256, 0, stream>>>(dinv, n);
    k_norm<<<(E + 255) / 256, 256, 0, stream>>>(row, col, dinv, nrm, E);

    // accum = x0 = item_emb[:n]
    k_copy4<<<((int)(nf / 4) + 255) / 256, 256, 0, stream>>>(emb, out, (int)(nf / 4));

    const float* x = emb;               // layer-0 input
    float* targets[3] = {xA, xB, xA};
    const int gemm_blocks    = (n + 63) / 64;
    const int scatter_blocks = E / 2;   // E*128 threads / 256
    const int nf_blocks      = ((int)nf + 255) / 256;
    for (int l = 0; l < 3; l++) {
        float* xn = targets[l];
        k_gemm<<<gemm_blocks, 256, 0, stream>>>(x, W + (size_t)l * D * D, h, n);
        hipMemsetAsync(xn, 0, nf * 4, stream);
        k_scatter<<<scatter_blocks, 256, 0, stream>>>(row, col, nrm, h, xn, E);
        k_finish <<<nf_blocks, 256, 0, stream>>>(h, dinv, b + (size_t)l * D, xn, out, n);
        x = xn;
    }
}

// Round 2
// 909.294 us; speedup vs baseline: 1.7805x; 1.7805x over previous
//
#include <hip/hip_runtime.h>
#include <hip/hip_bf16.h>

// GCN forward, pull-based (CSR) aggregation — no float atomics.
// out = sum_{i=0..3} x_i,  x_{i+1} = D^-1/2 (A+I) D^-1/2 (x_i W_i) + b_i
// n = 50001 nodes, D = 128 features, E = 800000 edges, 3 layers, fp32.

constexpr int NN = 50001;
constexpr int D  = 128;

// ---- CSR build ----
__global__ __launch_bounds__(256)
void k_deg_i(const int* __restrict__ col, int* __restrict__ deg, int E) {
    int e = blockIdx.x * 256 + threadIdx.x;
    if (e < E) atomicAdd(&deg[col[e]], 1);
}

__global__ __launch_bounds__(256)
void k_dinv(const int* __restrict__ deg, float* __restrict__ dinv, int n) {
    int v = blockIdx.x * 256 + threadIdx.x;
    if (v < n) dinv[v] = rsqrtf((float)deg[v] + 1.0f);   // +1 self loop
}

// single-block exclusive scan: row_ptr[0..n], row_ptr[n] = E
__global__ __launch_bounds__(1024)
void k_scan(const int* __restrict__ deg, int* __restrict__ row_ptr, int n) {
    __shared__ int smem[1024];
    __shared__ int base;
    if (threadIdx.x == 0) base = 0;
    __syncthreads();
    for (int start = 0; start < n; start += 1024) {
        int i = start + (int)threadIdx.x;
        int v = (i < n) ? deg[i] : 0;
        smem[threadIdx.x] = v;
        __syncthreads();
        for (int ofs = 1; ofs < 1024; ofs <<= 1) {
            int t = (threadIdx.x >= ofs) ? smem[threadIdx.x - ofs] : 0;
            __syncthreads();
            smem[threadIdx.x] += t;
            __syncthreads();
        }
        int excl = smem[threadIdx.x] - v;
        int b0 = base;
        if (i < n) row_ptr[i] = b0 + excl;
        __syncthreads();
        if (threadIdx.x == 0) base = b0 + smem[1023];
        __syncthreads();
    }
    if (threadIdx.x == 0) row_ptr[n] = base;
}

__global__ __launch_bounds__(256)
void k_fill(const int* __restrict__ row, const int* __restrict__ col,
            const int* __restrict__ row_ptr, int* __restrict__ cursor,
            const float* __restrict__ dinv,
            int* __restrict__ csr_src, float* __restrict__ csr_wt, int E) {
    int e = blockIdx.x * 256 + threadIdx.x;
    if (e < E) {
        int r = row[e], c = col[e];
        int p = row_ptr[c] + atomicAdd(&cursor[c], 1);
        csr_src[p] = r;
        csr_wt[p]  = dinv[r] * dinv[c];
    }
}

__global__ __launch_bounds__(256)
void k_copy4(const float* __restrict__ src, float* __restrict__ dst, int n4) {
    int i = blockIdx.x * 256 + threadIdx.x;
    if (i < n4) ((float4*)dst)[i] = ((const float4*)src)[i];
}

// ---- per-layer compute ----
// h[n,128] = x[n,128] @ W[128,128]; x tile (64 rows) in LDS, W float4-streamed (L2-hot).
__global__ __launch_bounds__(256)
void k_gemm(const float* __restrict__ x, const float* __restrict__ W,
            float* __restrict__ h, int n) {
    __shared__ float xs[64][D];
    int rowBase = blockIdx.x * 64;
    int tid = threadIdx.x;
    for (int i = tid; i < 64 * D / 4; i += 256) {
        int r  = rowBase + (i >> 5);
        int c4 = i & 31;
        float4 v = make_float4(0.f, 0.f, 0.f, 0.f);
        if (r < n) v = ((const float4*)x)[(size_t)r * (D / 4) + c4];
        ((float4*)xs)[i] = v;
    }
    __syncthreads();
    int cg = tid & 31;
    int rs = tid >> 5;
    for (int rr = rs; rr < 64; rr += 8) {
        int r = rowBase + rr;
        if (r >= n) break;
        float4 acc = make_float4(0.f, 0.f, 0.f, 0.f);
#pragma unroll 4
        for (int k = 0; k < D; k++) {
            float  xv = xs[rr][k];
            float4 w  = ((const float4*)W)[k * (D / 4) + cg];
            acc.x = fmaf(xv, w.x, acc.x);
            acc.y = fmaf(xv, w.y, acc.y);
            acc.z = fmaf(xv, w.z, acc.z);
            acc.w = fmaf(xv, w.w, acc.w);
        }
        ((float4*)h)[(size_t)r * (D / 4) + cg] = acc;
    }
}

// One wave per destination node; lane holds 2 features (float2).
// xn[c] = sum_in wt*h[src] + dinv[c]^2*h[c] + b ; out[c] += xn[c]
__global__ __launch_bounds__(256)
void k_pull(const int* __restrict__ rp, const int* __restrict__ src,
            const float* __restrict__ wt, const float* __restrict__ h,
            const float* __restrict__ dinv, const float* __restrict__ b,
            float* __restrict__ xn, float* __restrict__ out,
            int n, int write_xn) {
    int wave = (int)((blockIdx.x * 256 + threadIdx.x) >> 6);
    int lane = threadIdx.x & 63;
    if (wave >= n) return;
    const int c = wave;
    int s = rp[c], e = rp[c + 1];
    const float2* h2 = (const float2*)h;
    float2 acc = make_float2(0.f, 0.f);
    for (int j = s; j < e; j++) {
        int   r = src[j];
        float w = wt[j];
        float2 v = h2[(size_t)r * 64 + lane];
        acc.x = fmaf(v.x, w, acc.x);
        acc.y = fmaf(v.y, w, acc.y);
    }
    float di = dinv[c], d2 = di * di;
    float2 hv = h2[(size_t)c * 64 + lane];
    float2 bb = ((const float2*)b)[lane];
    acc.x = fmaf(hv.x, d2, acc.x) + bb.x;
    acc.y = fmaf(hv.y, d2, acc.y) + bb.y;
    size_t o = (size_t)c * 64 + lane;
    if (write_xn) ((float2*)xn)[o] = acc;
    float2 ov = ((float2*)out)[o];
    ov.x += acc.x;
    ov.y += acc.y;
    ((float2*)out)[o] = ov;
}

extern "C" void kernel_launch(void* const* d_in, const int* in_sizes, int n_in,
                              void* d_out, int out_size, void* d_ws, size_t ws_size,
                              hipStream_t stream) {
    const int*   edge = (const int*)d_in[0];    // [2, E]
    const float* emb  = (const float*)d_in[1];  // [100001, 128]
    const float* W    = (const float*)d_in[2];  // [3, 128, 128]
    const float* b    = (const float*)d_in[3];  // [3, 128]
    float* out = (float*)d_out;                 // [50001, 128]

    const int E = in_sizes[0] / 2;
    const int n = NN;
    const size_t nf = (size_t)n * D;
    const int* row = edge;
    const int* col = edge + E;

    // workspace carve-up
    char* ws = (char*)d_ws;
    size_t off = 0;
    auto carve = [&](size_t bytes) { char* p = ws + off; off = (off + bytes + 511) / 512 * 512; return p; };
    int*   deg     = (int*)  carve((size_t)n * 4);
    int*   cursor  = (int*)  carve((size_t)n * 4);
    int*   row_ptr = (int*)  carve((size_t)(n + 1) * 4);
    float* dinv    = (float*)carve((size_t)n * 4);
    int*   csr_src = (int*)  carve((size_t)E * 4);
    float* csr_wt  = (float*)carve((size_t)E * 4);
    float* h       = (float*)carve(nf * 4);
    float* xA      = (float*)carve(nf * 4);
    float* xB      = (float*)carve(nf * 4);

    // ---- CSR build (once; reused across 3 layers) ----
    hipMemsetAsync(deg, 0, (size_t)n * 4, stream);
    hipMemsetAsync(cursor, 0, (size_t)n * 4, stream);
    k_deg_i<<<(E + 255) / 256, 256, 0, stream>>>(col, deg, E);
    k_dinv <<<(n + 255) / 256, 256, 0, stream>>>(deg, dinv, n);
    k_scan <<<1, 1024, 0, stream>>>(deg, row_ptr, n);
    k_fill <<<(E + 255) / 256, 256, 0, stream>>>(row, col, row_ptr, cursor,
                                                 dinv, csr_src, csr_wt, E);

    // accum = x0 = item_emb[:n]
    k_copy4<<<((int)(nf / 4) + 255) / 256, 256, 0, stream>>>(emb, out, (int)(nf / 4));

    const float* x = emb;
    float* targets[3] = {xA, xB, xA};
    const int gemm_blocks = (n + 63) / 64;
    const int pull_blocks = (n + 3) / 4;     // 4 waves (nodes) per 256-block
    for (int l = 0; l < 3; l++) {
        float* xn = targets[l];
        k_gemm<<<gemm_blocks, 256, 0, stream>>>(x, W + (size_t)l * D * D, h, n);
        k_pull<<<pull_blocks, 256, 0, stream>>>(row_ptr, csr_src, csr_wt, h,
                                                dinv, b + (size_t)l * D,
                                                xn, out, n, (l < 2) ? 1 : 0);
        x = xn;
    }
}

// Round 3
// 480.845 us; speedup vs baseline: 3.3669x; 1.8910x over previous
//
#include <hip/hip_runtime.h>
#include <hip/hip_bf16.h>

// GCN forward, CSR pull aggregation + bf16 MFMA GEMM.
// out = sum_{i=0..3} x_i,  x_{i+1} = D^-1/2 (A+I) D^-1/2 (x_i W_i) + b_i
// n = 50001 nodes, D = 128, E = 800000 edges, 3 layers. fp32 in/out, bf16 internal.

constexpr int NN   = 50001;
constexpr int D    = 128;
constexpr int NPAD = 50048;          // 391 blocks * 128 rows

using bf16x8 = __attribute__((ext_vector_type(8))) short;
using f32x4  = __attribute__((ext_vector_type(4))) float;

__device__ __forceinline__ ushort f2b(float f) {         // fp32 -> bf16 RNE
    unsigned u = __float_as_uint(f);
    return (ushort)((u + 0x7FFFu + ((u >> 16) & 1u)) >> 16);
}
__device__ __forceinline__ float b2f(ushort u) {
    return __uint_as_float((unsigned)u << 16);
}

// ---------------- CSR build ----------------
__global__ __launch_bounds__(256)
void k_deg_i(const int* __restrict__ col, int* __restrict__ deg, int E) {
    int e = blockIdx.x * 256 + threadIdx.x;
    if (e < E) atomicAdd(&deg[col[e]], 1);
}

__global__ __launch_bounds__(256)
void k_dinv(const int* __restrict__ deg, float* __restrict__ dinv, int n) {
    int v = blockIdx.x * 256 + threadIdx.x;
    if (v < n) dinv[v] = rsqrtf((float)deg[v] + 1.0f);   // +1 self loop
}

// per-256-block sums of deg (zeros past n)
__global__ __launch_bounds__(256)
void k_bsum(const int* __restrict__ deg, int* __restrict__ bsum, int n) {
    __shared__ int sm[256];
    int i = blockIdx.x * 256 + threadIdx.x;
    sm[threadIdx.x] = (i < n) ? deg[i] : 0;
    __syncthreads();
    for (int ofs = 128; ofs > 0; ofs >>= 1) {
        if (threadIdx.x < ofs) sm[threadIdx.x] += sm[threadIdx.x + ofs];
        __syncthreads();
    }
    if (threadIdx.x == 0) bsum[blockIdx.x] = sm[0];
}

// exclusive scan of bsum[0..nb) (nb <= 256), single block
__global__ __launch_bounds__(256)
void k_bscan(const int* __restrict__ bsum, int* __restrict__ boff, int nb) {
    __shared__ int sm[256];
    int t = threadIdx.x;
    int v = (t < nb) ? bsum[t] : 0;
    sm[t] = v;
    __syncthreads();
    for (int ofs = 1; ofs < 256; ofs <<= 1) {
        int u = (t >= ofs) ? sm[t - ofs] : 0;
        __syncthreads();
        sm[t] += u;
        __syncthreads();
    }
    if (t < nb) boff[t] = sm[t] - v;
}

// row_ptr[i] = boff[block] + exclusive intra-block scan; covers i in [0, n]
__global__ __launch_bounds__(256)
void k_rowptr(const int* __restrict__ deg, const int* __restrict__ boff,
              int* __restrict__ row_ptr, int n) {
    __shared__ int sm[256];
    int t = threadIdx.x;
    int i = blockIdx.x * 256 + t;
    int v = (i < n) ? deg[i] : 0;
    sm[t] = v;
    __syncthreads();
    for (int ofs = 1; ofs < 256; ofs <<= 1) {
        int u = (t >= ofs) ? sm[t - ofs] : 0;
        __syncthreads();
        sm[t] += u;
        __syncthreads();
    }
    if (i <= n) row_ptr[i] = boff[blockIdx.x] + sm[t] - v;
}

__global__ __launch_bounds__(256)
void k_fill(const int* __restrict__ row, const int* __restrict__ col,
            const int* __restrict__ row_ptr, int* __restrict__ cursor,
            const float* __restrict__ dinv,
            int* __restrict__ csr_src, float* __restrict__ csr_wt, int E) {
    int e = blockIdx.x * 256 + threadIdx.x;
    if (e < E) {
        int r = row[e], c = col[e];
        int p = row_ptr[c] + atomicAdd(&cursor[c], 1);
        csr_src[p] = r;
        csr_wt[p]  = dinv[r] * dinv[c];
    }
}

// ---------------- init: out = emb[:n] (fp32), xb = bf16(emb[:n]), zero pad rows ----------------
__global__ __launch_bounds__(256)
void k_init(const float* __restrict__ emb, float* __restrict__ out,
            ushort* __restrict__ xb, int n) {
    int i4 = blockIdx.x * 256 + threadIdx.x;          // group of 4 floats
    if (i4 >= NPAD * (D / 4)) return;
    int row = i4 >> 5;
    if (row < n) {
        float4 v = ((const float4*)emb)[i4];
        ((float4*)out)[i4] = v;
        ushort4 b; b.x = f2b(v.x); b.y = f2b(v.y); b.z = f2b(v.z); b.w = f2b(v.w);
        ((ushort4*)xb)[i4] = b;
    } else {
        ((ushort4*)xb)[i4] = make_ushort4(0, 0, 0, 0);
    }
}

// Wt[l][c][k] = bf16(W[l][k][c])   (transposed per layer)
__global__ __launch_bounds__(256)
void k_wt(const float* __restrict__ W, ushort* __restrict__ Wt) {
    int idx = blockIdx.x * 256 + threadIdx.x;
    if (idx >= 3 * D * D) return;
    int l = idx >> 14, rem = idx & 16383;
    int c = rem >> 7, k = rem & 127;
    Wt[idx] = f2b(W[l * D * D + k * D + c]);
}

// ---------------- MFMA GEMM: h[NPAD,128](bf16) = xb[NPAD,128](bf16) @ W ----------------
// block = 256 threads = 4 waves; wave computes 32 rows x 128 cols; Wt (transposed) in LDS.
constexpr int WT_LD = 136;   // padded row stride (shorts) to break bank conflicts
__global__ __launch_bounds__(256)
void k_gemm_mfma(const ushort* __restrict__ xb, const ushort* __restrict__ WtL,
                 ushort* __restrict__ h, int n) {
    __shared__ ushort wlds[D * WT_LD];
    for (int idx = threadIdx.x; idx < D * (D / 8); idx += 256) {   // 2048 chunks of 8 shorts
        int r = idx >> 4, c8 = (idx & 15) * 8;
        *(uint4*)&wlds[r * WT_LD + c8] = *(const uint4*)&WtL[r * D + c8];
    }
    __syncthreads();

    int wave = threadIdx.x >> 6, lane = threadIdx.x & 63;
    int q = lane >> 4, i = lane & 15;
    int waveRow = blockIdx.x * 128 + wave * 32;

    // A fragments: 2 row-tiles x 4 K-steps, A[m=i][k=ks*32+q*8+j]
    bf16x8 a[2][4];
#pragma unroll
    for (int rt = 0; rt < 2; rt++) {
        const ushort* base = &xb[(size_t)(waveRow + rt * 16 + i) * D + q * 8];
#pragma unroll
        for (int ks = 0; ks < 4; ks++)
            a[rt][ks] = *(const bf16x8*)(base + ks * 32);
    }

    f32x4 acc[2][8] = {};
#pragma unroll
    for (int ct = 0; ct < 8; ct++) {
        const ushort* wbase = &wlds[(ct * 16 + i) * WT_LD + q * 8];
#pragma unroll
        for (int ks = 0; ks < 4; ks++) {
            bf16x8 bfr = *(const bf16x8*)(wbase + ks * 32);   // B[k=ks*32+q*8+j][nn=ct*16+i]
            acc[0][ct] = __builtin_amdgcn_mfma_f32_16x16x32_bf16(a[0][ks], bfr, acc[0][ct], 0, 0, 0);
            acc[1][ct] = __builtin_amdgcn_mfma_f32_16x16x32_bf16(a[1][ks], bfr, acc[1][ct], 0, 0, 0);
        }
    }

    // C/D: col = ct*16 + i, row = rt*16 + q*4 + r4
#pragma unroll
    for (int rt = 0; rt < 2; rt++)
#pragma unroll
        for (int r4 = 0; r4 < 4; r4++) {
            int row = waveRow + rt * 16 + q * 4 + r4;
            if (row < n) {
#pragma unroll
                for (int ct = 0; ct < 8; ct++)
                    h[(size_t)row * D + ct * 16 + i] = f2b(acc[rt][ct][r4]);
            }
        }
}

// ---------------- pull aggregation ----------------
// one wave per destination node; lane holds features {2*lane, 2*lane+1}
// val = sum_in wt*h[src] + dinv^2*h[c] + b ; out[c] += val ; xb[c] = bf16(val)
__global__ __launch_bounds__(256)
void k_pull(const int* __restrict__ rp, const int* __restrict__ src,
            const float* __restrict__ wt, const ushort* __restrict__ h,
            const float* __restrict__ dinv, const float* __restrict__ b,
            ushort* __restrict__ xb, float* __restrict__ out,
            int n, int write_xb) {
    int c = (int)((blockIdx.x * 256 + threadIdx.x) >> 6);
    int lane = threadIdx.x & 63;
    if (c >= n) return;
    int s = rp[c], e = rp[c + 1];
    float ax = 0.f, ay = 0.f;
    for (int j = s; j < e; j++) {
        int   r = src[j];
        float w = wt[j];
        ushort2 v = *(const ushort2*)&h[(size_t)r * D + 2 * lane];
        ax = fmaf(b2f(v.x), w, ax);
        ay = fmaf(b2f(v.y), w, ay);
    }
    float di = dinv[c], d2 = di * di;
    ushort2 hv = *(const ushort2*)&h[(size_t)c * D + 2 * lane];
    float2  bb = ((const float2*)b)[lane];
    ax = fmaf(b2f(hv.x), d2, ax) + bb.x;
    ay = fmaf(b2f(hv.y), d2, ay) + bb.y;
    size_t o = (size_t)c * 64 + lane;
    float2 ov = ((float2*)out)[o];
    ov.x += ax; ov.y += ay;
    ((float2*)out)[o] = ov;
    if (write_xb) {
        ushort2 xv; xv.x = f2b(ax); xv.y = f2b(ay);
        ((ushort2*)xb)[o] = xv;
    }
}

extern "C" void kernel_launch(void* const* d_in, const int* in_sizes, int n_in,
                              void* d_out, int out_size, void* d_ws, size_t ws_size,
                              hipStream_t stream) {
    const int*   edge = (const int*)d_in[0];    // [2, E]
    const float* emb  = (const float*)d_in[1];  // [100001, 128]
    const float* W    = (const float*)d_in[2];  // [3, 128, 128]
    const float* b    = (const float*)d_in[3];  // [3, 128]
    float* out = (float*)d_out;                 // [50001, 128] fp32

    const int E = in_sizes[0] / 2;
    const int n = NN;
    const int* row = edge;
    const int* col = edge + E;

    char* ws = (char*)d_ws;
    size_t off = 0;
    auto carve = [&](size_t bytes) { char* p = ws + off; off = (off + bytes + 511) / 512 * 512; return p; };
    int*    deg     = (int*)   carve((size_t)n * 4);
    int*    cursor  = (int*)   carve((size_t)n * 4);
    int*    row_ptr = (int*)   carve((size_t)(n + 1) * 4);
    float*  dinv    = (float*) carve((size_t)n * 4);
    int*    bsum    = (int*)   carve(256 * 4);
    int*    boff    = (int*)   carve(256 * 4);
    int*    csr_src = (int*)   carve((size_t)E * 4);
    float*  csr_wt  = (float*) carve((size_t)E * 4);
    ushort* Wt      = (ushort*)carve((size_t)3 * D * D * 2);
    ushort* xb      = (ushort*)carve((size_t)NPAD * D * 2);
    ushort* h       = (ushort*)carve((size_t)NPAD * D * 2);

    const int NB = (n + 255) / 256;   // 196

    // CSR build (once per launch; reused by all 3 layers)
    hipMemsetAsync(deg, 0, (size_t)n * 4, stream);
    hipMemsetAsync(cursor, 0, (size_t)n * 4, stream);
    k_deg_i <<<(E + 255) / 256, 256, 0, stream>>>(col, deg, E);
    k_dinv  <<<NB, 256, 0, stream>>>(deg, dinv, n);
    k_bsum  <<<NB, 256, 0, stream>>>(deg, bsum, n);
    k_bscan <<<1, 256, 0, stream>>>(bsum, boff, NB);
    k_rowptr<<<NB, 256, 0, stream>>>(deg, boff, row_ptr, n);
    k_fill  <<<(E + 255) / 256, 256, 0, stream>>>(row, col, row_ptr, cursor,
                                                  dinv, csr_src, csr_wt, E);

    // out = x0 ; xb = bf16(x0) ; Wt = bf16(W^T)
    k_init<<<(NPAD * (D / 4) + 255) / 256, 256, 0, stream>>>(emb, out, xb, n);
    k_wt  <<<(3 * D * D + 255) / 256, 256, 0, stream>>>(W, Wt);

    const int gemm_blocks = NPAD / 128;          // 391
    const int pull_blocks = (n + 3) / 4;         // 4 nodes per block
    for (int l = 0; l < 3; l++) {
        k_gemm_mfma<<<gemm_blocks, 256, 0, stream>>>(xb, Wt + (size_t)l * D * D, h, n);
        k_pull<<<pull_blocks, 256, 0, stream>>>(row_ptr, csr_src, csr_wt, h,
                                                dinv, b + (size_t)l * D,
                                                xb, out, n, (l < 2) ? 1 : 0);
    }
}

// Round 5
// 362.492 us; speedup vs baseline: 4.4662x; 1.3265x over previous
//
#include <hip/hip_runtime.h>
#include <hip/hip_bf16.h>

// GCN forward, CSR pull aggregation (unroll-8 gathers) + bf16 MFMA GEMM.
// out = sum_{i=0..3} x_i,  x_{i+1} = D^-1/2 (A+I) D^-1/2 (x_i W_i) + b_i
// n = 50001 nodes, D = 128, E = 800000 edges, 3 layers. fp32 in/out, bf16 internal.

constexpr int NN   = 50001;
constexpr int D    = 128;
constexpr int NPAD = 50048;          // 391 blocks * 128 rows

using bf16x8 = __attribute__((ext_vector_type(8))) short;
using f32x4  = __attribute__((ext_vector_type(4))) float;
using f32x2  = __attribute__((ext_vector_type(2))) float;   // clang vector (nontemporal-ok)

__device__ __forceinline__ ushort f2b(float f) {         // fp32 -> bf16 RNE
    unsigned u = __float_as_uint(f);
    return (ushort)((u + 0x7FFFu + ((u >> 16) & 1u)) >> 16);
}
__device__ __forceinline__ float b2f(ushort u) {
    return __uint_as_float((unsigned)u << 16);
}

// ---------------- CSR build ----------------
__global__ __launch_bounds__(256)
void k_deg_i(const int* __restrict__ col, int* __restrict__ deg, int E) {
    int e = blockIdx.x * 256 + threadIdx.x;
    if (e < E) atomicAdd(&deg[col[e]], 1);
}

__global__ __launch_bounds__(256)
void k_dinv(const int* __restrict__ deg, float* __restrict__ dinv, int n) {
    int v = blockIdx.x * 256 + threadIdx.x;
    if (v < n) dinv[v] = rsqrtf((float)deg[v] + 1.0f);   // +1 self loop
}

// per-256-block sums of deg (zeros past n)
__global__ __launch_bounds__(256)
void k_bsum(const int* __restrict__ deg, int* __restrict__ bsum, int n) {
    __shared__ int sm[256];
    int i = blockIdx.x * 256 + threadIdx.x;
    sm[threadIdx.x] = (i < n) ? deg[i] : 0;
    __syncthreads();
    for (int ofs = 128; ofs > 0; ofs >>= 1) {
        if (threadIdx.x < ofs) sm[threadIdx.x] += sm[threadIdx.x + ofs];
        __syncthreads();
    }
    if (threadIdx.x == 0) bsum[blockIdx.x] = sm[0];
}

// exclusive scan of bsum[0..nb) (nb <= 256), single block
__global__ __launch_bounds__(256)
void k_bscan(const int* __restrict__ bsum, int* __restrict__ boff, int nb) {
    __shared__ int sm[256];
    int t = threadIdx.x;
    int v = (t < nb) ? bsum[t] : 0;
    sm[t] = v;
    __syncthreads();
    for (int ofs = 1; ofs < 256; ofs <<= 1) {
        int u = (t >= ofs) ? sm[t - ofs] : 0;
        __syncthreads();
        sm[t] += u;
        __syncthreads();
    }
    if (t < nb) boff[t] = sm[t] - v;
}

// row_ptr[i] = boff[block] + exclusive intra-block scan; also cursor[i] = row_ptr[i]
__global__ __launch_bounds__(256)
void k_rowptr(const int* __restrict__ deg, const int* __restrict__ boff,
              int* __restrict__ row_ptr, int* __restrict__ cursor, int n) {
    __shared__ int sm[256];
    int t = threadIdx.x;
    int i = blockIdx.x * 256 + t;
    int v = (i < n) ? deg[i] : 0;
    sm[t] = v;
    __syncthreads();
    for (int ofs = 1; ofs < 256; ofs <<= 1) {
        int u = (t >= ofs) ? sm[t - ofs] : 0;
        __syncthreads();
        sm[t] += u;
        __syncthreads();
    }
    int rp = boff[blockIdx.x] + sm[t] - v;
    if (i <= n) row_ptr[i] = rp;
    if (i < n)  cursor[i]  = rp;
}

// meta[p] = {src, float_bits(dinv[r]*dinv[c])} — one 8B record per edge
__global__ __launch_bounds__(256)
void k_fill(const int* __restrict__ row, const int* __restrict__ col,
            int* __restrict__ cursor, const float* __restrict__ dinv,
            int2* __restrict__ meta, int E) {
    int e = blockIdx.x * 256 + threadIdx.x;
    if (e < E) {
        int r = row[e], c = col[e];
        int p = atomicAdd(&cursor[c], 1);
        meta[p] = make_int2(r, __float_as_int(dinv[r] * dinv[c]));
    }
}

// ---------------- init: out = emb[:n] (fp32), xb = bf16(emb[:n]), zero pad rows ----------------
__global__ __launch_bounds__(256)
void k_init(const float* __restrict__ emb, float* __restrict__ out,
            ushort* __restrict__ xb, int n) {
    int i4 = blockIdx.x * 256 + threadIdx.x;          // group of 4 floats
    if (i4 >= NPAD * (D / 4)) return;
    int row = i4 >> 5;
    if (row < n) {
        float4 v = ((const float4*)emb)[i4];
        ((float4*)out)[i4] = v;
        ushort4 b; b.x = f2b(v.x); b.y = f2b(v.y); b.z = f2b(v.z); b.w = f2b(v.w);
        ((ushort4*)xb)[i4] = b;
    } else {
        ((ushort4*)xb)[i4] = make_ushort4(0, 0, 0, 0);
    }
}

// Wt[l][c][k] = bf16(W[l][k][c])   (transposed per layer)
__global__ __launch_bounds__(256)
void k_wt(const float* __restrict__ W, ushort* __restrict__ Wt) {
    int idx = blockIdx.x * 256 + threadIdx.x;
    if (idx >= 3 * D * D) return;
    int l = idx >> 14, rem = idx & 16383;
    int c = rem >> 7, k = rem & 127;
    Wt[idx] = f2b(W[l * D * D + k * D + c]);
}

// ---------------- MFMA GEMM: h[NPAD,128](bf16) = xb[NPAD,128](bf16) @ W ----------------
constexpr int WT_LD = 136;   // padded row stride (shorts) to break bank conflicts
__global__ __launch_bounds__(256)
void k_gemm_mfma(const ushort* __restrict__ xb, const ushort* __restrict__ WtL,
                 ushort* __restrict__ h, int n) {
    __shared__ ushort wlds[D * WT_LD];
    for (int idx = threadIdx.x; idx < D * (D / 8); idx += 256) {
        int r = idx >> 4, c8 = (idx & 15) * 8;
        *(uint4*)&wlds[r * WT_LD + c8] = *(const uint4*)&WtL[r * D + c8];
    }
    __syncthreads();

    int wave = threadIdx.x >> 6, lane = threadIdx.x & 63;
    int q = lane >> 4, i = lane & 15;
    int waveRow = blockIdx.x * 128 + wave * 32;

    bf16x8 a[2][4];
#pragma unroll
    for (int rt = 0; rt < 2; rt++) {
        const ushort* base = &xb[(size_t)(waveRow + rt * 16 + i) * D + q * 8];
#pragma unroll
        for (int ks = 0; ks < 4; ks++)
            a[rt][ks] = *(const bf16x8*)(base + ks * 32);
    }

    f32x4 acc[2][8] = {};
#pragma unroll
    for (int ct = 0; ct < 8; ct++) {
        const ushort* wbase = &wlds[(ct * 16 + i) * WT_LD + q * 8];
#pragma unroll
        for (int ks = 0; ks < 4; ks++) {
            bf16x8 bfr = *(const bf16x8*)(wbase + ks * 32);
            acc[0][ct] = __builtin_amdgcn_mfma_f32_16x16x32_bf16(a[0][ks], bfr, acc[0][ct], 0, 0, 0);
            acc[1][ct] = __builtin_amdgcn_mfma_f32_16x16x32_bf16(a[1][ks], bfr, acc[1][ct], 0, 0, 0);
        }
    }

#pragma unroll
    for (int rt = 0; rt < 2; rt++)
#pragma unroll
        for (int r4 = 0; r4 < 4; r4++) {
            int row = waveRow + rt * 16 + q * 4 + r4;
            if (row < n) {
#pragma unroll
                for (int ct = 0; ct < 8; ct++)
                    h[(size_t)row * D + ct * 16 + i] = f2b(acc[rt][ct][r4]);
            }
        }
}

// ---------------- pull aggregation ----------------
// one wave per destination node; lane holds features {2*lane, 2*lane+1}
// edge loop unrolled x8: 8 metas + 8 row-gathers issued before any FMA -> 8 loads in flight.
__global__ __launch_bounds__(256)
void k_pull(const int* __restrict__ rp, const int2* __restrict__ meta,
            const ushort* __restrict__ h,
            const float* __restrict__ dinv, const float* __restrict__ b,
            ushort* __restrict__ xb, float* __restrict__ out,
            int n, int write_xb) {
    int c = (int)((blockIdx.x * 256 + threadIdx.x) >> 6);
    int lane = threadIdx.x & 63;
    if (c >= n) return;
    int s = rp[c], e = rp[c + 1];
    float ax = 0.f, ay = 0.f;
    int j = s;
    for (; j + 8 <= e; j += 8) {
        int2 m[8];
        ushort2 v[8];
#pragma unroll
        for (int u = 0; u < 8; u++) m[u] = meta[j + u];
#pragma unroll
        for (int u = 0; u < 8; u++)
            v[u] = *(const ushort2*)&h[(size_t)m[u].x * D + 2 * lane];
#pragma unroll
        for (int u = 0; u < 8; u++) {
            float w = __int_as_float(m[u].y);
            ax = fmaf(b2f(v[u].x), w, ax);
            ay = fmaf(b2f(v[u].y), w, ay);
        }
    }
    for (; j < e; j++) {
        int2 m = meta[j];
        float w = __int_as_float(m.y);
        ushort2 v = *(const ushort2*)&h[(size_t)m.x * D + 2 * lane];
        ax = fmaf(b2f(v.x), w, ax);
        ay = fmaf(b2f(v.y), w, ay);
    }
    float di = dinv[c], d2 = di * di;
    ushort2 hv = *(const ushort2*)&h[(size_t)c * D + 2 * lane];
    float2  bb = ((const float2*)b)[lane];
    ax = fmaf(b2f(hv.x), d2, ax) + bb.x;
    ay = fmaf(b2f(hv.y), d2, ay) + bb.y;
    size_t o = (size_t)c * 64 + lane;
    f32x2 ov = __builtin_nontemporal_load((const f32x2*)out + o);
    ov.x += ax; ov.y += ay;
    __builtin_nontemporal_store(ov, (f32x2*)out + o);
    if (write_xb) {
        ushort2 xv; xv.x = f2b(ax); xv.y = f2b(ay);
        ((ushort2*)xb)[o] = xv;
    }
}

extern "C" void kernel_launch(void* const* d_in, const int* in_sizes, int n_in,
                              void* d_out, int out_size, void* d_ws, size_t ws_size,
                              hipStream_t stream) {
    const int*   edge = (const int*)d_in[0];    // [2, E]
    const float* emb  = (const float*)d_in[1];  // [100001, 128]
    const float* W    = (const float*)d_in[2];  // [3, 128, 128]
    const float* b    = (const float*)d_in[3];  // [3, 128]
    float* out = (float*)d_out;                 // [50001, 128] fp32

    const int E = in_sizes[0] / 2;
    const int n = NN;
    const int* row = edge;
    const int* col = edge + E;

    char* ws = (char*)d_ws;
    size_t off = 0;
    auto carve = [&](size_t bytes) { char* p = ws + off; off = (off + bytes + 511) / 512 * 512; return p; };
    int*    deg     = (int*)   carve((size_t)n * 4);
    int*    cursor  = (int*)   carve((size_t)n * 4);
    int*    row_ptr = (int*)   carve((size_t)(n + 1) * 4);
    float*  dinv    = (float*) carve((size_t)n * 4);
    int*    bsum    = (int*)   carve(256 * 4);
    int*    boff    = (int*)   carve(256 * 4);
    int2*   meta    = (int2*)  carve((size_t)E * 8);
    ushort* Wt      = (ushort*)carve((size_t)3 * D * D * 2);
    ushort* xb      = (ushort*)carve((size_t)NPAD * D * 2);
    ushort* h       = (ushort*)carve((size_t)NPAD * D * 2);

    const int NB = (n + 255) / 256;   // 196

    // CSR build (once per launch; reused by all 3 layers)
    (void)hipMemsetAsync(deg, 0, (size_t)n * 4, stream);
    k_deg_i <<<(E + 255) / 256, 256, 0, stream>>>(col, deg, E);
    k_dinv  <<<NB, 256, 0, stream>>>(deg, dinv, n);
    k_bsum  <<<NB, 256, 0, stream>>>(deg, bsum, n);
    k_bscan <<<1, 256, 0, stream>>>(bsum, boff, NB);
    k_rowptr<<<NB, 256, 0, stream>>>(deg, boff, row_ptr, cursor, n);
    k_fill  <<<(E + 255) / 256, 256, 0, stream>>>(row, col, cursor, dinv, meta, E);

    // out = x0 ; xb = bf16(x0) ; Wt = bf16(W^T)
    k_init<<<(NPAD * (D / 4) + 255) / 256, 256, 0, stream>>>(emb, out, xb, n);
    k_wt  <<<(3 * D * D + 255) / 256, 256, 0, stream>>>(W, Wt);

    const int gemm_blocks = NPAD / 128;          // 391
    const int pull_blocks = (n + 3) / 4;         // 4 nodes per block
    for (int l = 0; l < 3; l++) {
        k_gemm_mfma<<<gemm_blocks, 256, 0, stream>>>(xb, Wt + (size_t)l * D * D, h, n);
        k_pull<<<pull_blocks, 256, 0, stream>>>(row_ptr, meta, h,
                                                dinv, b + (size_t)l * D,
                                                xb, out, n, (l < 2) ? 1 : 0);
    }
}